// Round 8
// baseline (1145.024 us; speedup 1.0000x reference)
//
#include <hip/hip_runtime.h>

// ---------- types ----------
typedef __attribute__((ext_vector_type(8))) short bf16x8;
typedef __attribute__((ext_vector_type(4))) float f32x4;

static __device__ __forceinline__ unsigned short f2bf(float x) {
    unsigned int u = __float_as_uint(x);
    u += 0x7fffu + ((u >> 16) & 1u);   // RTNE, finite inputs
    return (unsigned short)(u >> 16);
}

// Workgroup barrier WITHOUT vmcnt drain: LDS ordering only.
// Safe when no global-memory producer/consumer relationship crosses the barrier.
static __device__ __forceinline__ void barrier_lds_only() {
    __asm__ volatile("s_waitcnt lgkmcnt(0)\n\ts_barrier" ::: "memory");
}

// ---------- K0: four fp32->bf16 transposes in one launch ----------
__global__ void transpose4(const float* __restrict__ s0, const float* __restrict__ s1,
                           const float* __restrict__ s2, const float* __restrict__ s3,
                           unsigned short* __restrict__ d0, unsigned short* __restrict__ d1,
                           unsigned short* __restrict__ d2, unsigned short* __restrict__ d3) {
    int which = blockIdx.y;
    const float* src = which == 0 ? s0 : which == 1 ? s1 : which == 2 ? s2 : s3;
    unsigned short* dst = which == 0 ? d0 : which == 1 ? d1 : which == 2 ? d2 : d3;
    int K = (which == 0) ? 512 : 256;
    int idx = blockIdx.x * 256 + threadIdx.x;
    if (idx >= K * 256) return;
    int k = idx >> 8;          // N = 256
    int n = idx & 255;
    dst[n * K + k] = f2bf(src[idx]);
}

// ---------- GEMM: bf16 MFMA, C = A[M,K] @ Bt[N,K]^T + bias ----------
// Stores output TRANSPOSED as CT[b][n][t] (b = m>>9, t = m&511), so the
// scan can read 4 consecutive timesteps per thread as one float4.
template<bool GATHER>
__global__ __launch_bounds__(256, 4) void gemm_mfma(
    const void* __restrict__ Aptr, const int* __restrict__ tokens,
    const unsigned short* __restrict__ Bt, const float* __restrict__ bias,
    float* __restrict__ C, int M, int N, int K)
{
    const int bn0 = blockIdx.x * 64;
    const int m0  = blockIdx.y * 64;
    const int tid = threadIdx.x;

    __shared__ unsigned short As[64 * 40];
    __shared__ unsigned short Bs[64 * 40];
    __shared__ int tok[64];

    if (GATHER) {
        if (tid < 64) tok[tid] = tokens[m0 + tid];
        __syncthreads();
    }

    const int r  = tid >> 2;
    const int c0 = (tid & 3) * 8;
    const int w  = tid >> 6;
    const int L  = tid & 63;
    const int ml = L & 15;
    const int q  = L >> 4;
    const int kq = q * 8;

    f32x4 acc[4] = {};

    for (int k0 = 0; k0 < K; k0 += 32) {
        unsigned short tmp[8];
        if (GATHER) {
            const float* src = (const float*)Aptr + (size_t)tok[r] * K + k0 + c0;
            float4 f0 = *(const float4*)(src);
            float4 f1 = *(const float4*)(src + 4);
            tmp[0]=f2bf(f0.x); tmp[1]=f2bf(f0.y); tmp[2]=f2bf(f0.z); tmp[3]=f2bf(f0.w);
            tmp[4]=f2bf(f1.x); tmp[5]=f2bf(f1.y); tmp[6]=f2bf(f1.z); tmp[7]=f2bf(f1.w);
        } else {
            const unsigned short* src = (const unsigned short*)Aptr + (size_t)(m0 + r) * K + k0 + c0;
            *(uint4*)tmp = *(const uint4*)src;
        }
        *(uint4*)&As[r * 40 + c0] = *(const uint4*)tmp;
        *(uint4*)&Bs[r * 40 + c0] = *(const uint4*)(Bt + (size_t)(bn0 + r) * K + k0 + c0);
        __syncthreads();

        bf16x8 av = *(const bf16x8*)&As[(16 * w + ml) * 40 + kq];
#pragma unroll
        for (int ns = 0; ns < 4; ++ns) {
            bf16x8 bv = *(const bf16x8*)&Bs[(ns * 16 + ml) * 40 + kq];
            acc[ns] = __builtin_amdgcn_mfma_f32_16x16x32_bf16(av, bv, acc[ns], 0, 0, 0);
        }
        __syncthreads();
    }

    // Transposed epilogue: CT[b][gn][t]; acc reg rr <-> t = tbase+rr -> float4 store.
    const int bb    = m0 >> 9;
    const int tbase = (m0 & 511) + 16 * w + q * 4;
#pragma unroll
    for (int ns = 0; ns < 4; ++ns) {
        int gn = bn0 + ns * 16 + ml;
        float bv = bias[gn];
        float4 v = { acc[ns][0] + bv, acc[ns][1] + bv, acc[ns][2] + bv, acc[ns][3] + bv };
        *(float4*)&C[(size_t)bb * 131072 + (size_t)gn * 512 + tbase] = v;
    }
}

// ---------- one chain's step: z = h_{t-1} @ U (this wave's 64 cols), tanh, writes ----------
template<bool SEQ>
static __device__ __forceinline__ float scan_chain_step(
    const unsigned short* __restrict__ hread,   // &hsh[cur][c][q*8]
    unsigned short* __restrict__ hwrite,        // &hsh[cur^1][c][col]
    const bf16x8 (&ufrag)[4][8], int q, float xv,
    unsigned short* __restrict__ op)            // SEQ store slot (or ignored)
{
    const f32x4 zf = {0.f, 0.f, 0.f, 0.f};
    bf16x8 af[8];
#pragma unroll
    for (int kt = 0; kt < 8; ++kt)
        af[kt] = *(const bf16x8*)(hread + kt * 32);
    f32x4 accA[4], accB[4];
#pragma unroll
    for (int i = 0; i < 4; ++i)
        accA[i] = __builtin_amdgcn_mfma_f32_16x16x32_bf16(af[0], ufrag[i][0], zf, 0, 0, 0);
#pragma unroll
    for (int i = 0; i < 4; ++i)
        accB[i] = __builtin_amdgcn_mfma_f32_16x16x32_bf16(af[1], ufrag[i][1], zf, 0, 0, 0);
#pragma unroll
    for (int kt = 2; kt < 8; kt += 2) {
#pragma unroll
        for (int i = 0; i < 4; ++i)
            accA[i] = __builtin_amdgcn_mfma_f32_16x16x32_bf16(af[kt], ufrag[i][kt], accA[i], 0, 0, 0);
#pragma unroll
        for (int i = 0; i < 4; ++i)
            accB[i] = __builtin_amdgcn_mfma_f32_16x16x32_bf16(af[kt + 1], ufrag[i][kt + 1], accB[i], 0, 0, 0);
    }
    float zA = (q == 0) ? accA[0][0] : (q == 1) ? accA[1][0] : (q == 2) ? accA[2][0] : accA[3][0];
    float zB = (q == 0) ? accB[0][0] : (q == 1) ? accB[1][0] : (q == 2) ? accB[2][0] : accB[3][0];
    float z  = zA + zB + xv;
    float e  = __expf(2.f * z);               // tanh(z) = 1 - 2/(e^{2z}+1); inf-safe
    float hn = 1.f - 2.f * __builtin_amdgcn_rcpf(e + 1.f);
    unsigned short hb = f2bf(hn);
    *hwrite = hb;
    if (SEQ) *op = hb;
    return hn;
}

// ---------- MFMA scan, 2 INTERLEAVED CHAINS: one WG (256 thr) per TWO batch rows ----------
// Each step runs both rows' matvec+tanh back-to-back, then ONE lds-only barrier.
// Chain 1's LDS reads / MFMAs issue inside chain 0's dependency stalls; the
// barrier + post-barrier latency block is amortized over 2 rows. ufrag shared.
template<bool SEQ>
__global__ __launch_bounds__(256, 1) void rnn_scan_mfma2(
    const float* __restrict__ xwT,          // [64][256][512] f32 (transposed)
    const unsigned short* __restrict__ Ut,  // [256][256] bf16, Ut[n][k] = U[k][n]
    unsigned short* __restrict__ out_seq,   // bf16 [64][512][256]  (SEQ)
    float* __restrict__ out_last)           // f32 [64][256]        (!SEQ)
{
    const int b0  = blockIdx.x * 2;
    const int tid = threadIdx.x;
    const int w   = tid >> 6;       // wave 0..3
    const int L   = tid & 63;
    const int col = w * 64 + L;     // this thread's output column (L = q*16+ml)
    const int q   = L >> 4;
    const int ml  = L & 15;

    __shared__ unsigned short hsh[2][2][256];   // [buf][chain][col]

    // B-frags: U columns for this wave's 4 n-tiles, all 8 k-tiles (shared by both chains)
    bf16x8 ufrag[4][8];
#pragma unroll
    for (int i = 0; i < 4; ++i) {
        const unsigned short* up = Ut + (size_t)((w * 4 + i) * 16 + ml) * 256 + q * 8;
#pragma unroll
        for (int kt = 0; kt < 8; ++kt)
            ufrag[i][kt] = *(const bf16x8*)(up + kt * 32);
    }

    hsh[0][0][tid] = 0;   // bf16 +0.0
    hsh[0][1][tid] = 0;

    const float* xb0 = xwT + (size_t)(b0 + 0) * 131072 + (size_t)col * 512;
    const float* xb1 = xwT + (size_t)(b0 + 1) * 131072 + (size_t)col * 512;
    unsigned short* op0 = SEQ ? out_seq + (size_t)(b0 + 0) * 131072 + col : nullptr;
    unsigned short* op1 = SEQ ? out_seq + (size_t)(b0 + 1) * 131072 + col : nullptr;

    // chunked xw: float4 = 4 timesteps, 2 groups in flight per chain
    float4 ca0 = *(const float4*)(xb0);
    float4 ca1 = *(const float4*)(xb0 + 4);
    float4 cb0 = *(const float4*)(xb1);
    float4 cb1 = *(const float4*)(xb1 + 4);

    float last0 = 0.f, last1 = 0.f;
    __syncthreads();

#define STEP2(CUR, XV0, XV1)                                                          \
    {                                                                                 \
        last0 = scan_chain_step<SEQ>(&hsh[CUR][0][q * 8], &hsh[(CUR) ^ 1][0][col],    \
                                     ufrag, q, (XV0), op0);                           \
        last1 = scan_chain_step<SEQ>(&hsh[CUR][1][q * 8], &hsh[(CUR) ^ 1][1][col],    \
                                     ufrag, q, (XV1), op1);                           \
        if (SEQ) { op0 += 256; op1 += 256; }                                          \
        barrier_lds_only();                                                           \
    }

    // steady state: groups 0..125 consumed; loads issued 2 groups ahead
    for (int g = 0; g < 126; g += 2) {
        {
            float4 n0 = *(const float4*)(xb0 + 4 * g + 8);
            float4 n1 = *(const float4*)(xb1 + 4 * g + 8);
            STEP2(0, ca0.x, cb0.x)
            STEP2(1, ca0.y, cb0.y)
            STEP2(0, ca0.z, cb0.z)
            STEP2(1, ca0.w, cb0.w)
            ca0 = n0; cb0 = n1;
        }
        {
            float4 n0 = *(const float4*)(xb0 + 4 * g + 12);
            float4 n1 = *(const float4*)(xb1 + 4 * g + 12);
            STEP2(0, ca1.x, cb1.x)
            STEP2(1, ca1.y, cb1.y)
            STEP2(0, ca1.z, cb1.z)
            STEP2(1, ca1.w, cb1.w)
            ca1 = n0; cb1 = n1;
        }
    }
    // epilogue: groups 126, 127 (t = 504..511)
    STEP2(0, ca0.x, cb0.x)
    STEP2(1, ca0.y, cb0.y)
    STEP2(0, ca0.z, cb0.z)
    STEP2(1, ca0.w, cb0.w)
    STEP2(0, ca1.x, cb1.x)
    STEP2(1, ca1.y, cb1.y)
    STEP2(0, ca1.z, cb1.z)
    STEP2(1, ca1.w, cb1.w)
#undef STEP2

    if (!SEQ) {
        out_last[(b0 + 0) * 256 + col] = last0;
        out_last[(b0 + 1) * 256 + col] = last1;
    }
}

// ---------- head: softmax(h2 @ Wd + bd) ----------
__global__ void head_kernel(const float* __restrict__ h2, const float* __restrict__ Wd,
                            const float* __restrict__ bd, float* __restrict__ out)
{
    int tid = threadIdx.x;         // 128 threads: b = tid>>1, c = tid&1
    int b = tid >> 1, c = tid & 1;
    float s = bd[c];
    for (int jj = 0; jj < 256; ++jj) s = fmaf(h2[b * 256 + jj], Wd[jj * 2 + c], s);
    __shared__ float lg[128];
    lg[tid] = s;
    __syncthreads();
    float o0 = lg[b * 2 + 0], o1 = lg[b * 2 + 1];
    float m = fmaxf(o0, o1);
    float z = __expf(o0 - m) + __expf(o1 - m);
    out[tid] = __expf(s - m) * __builtin_amdgcn_rcpf(z);
}

// ---------- launch ----------
extern "C" void kernel_launch(void* const* d_in, const int* in_sizes, int n_in,
                              void* d_out, int out_size, void* d_ws, size_t ws_size,
                              hipStream_t stream) {
    const int*   tokens = (const int*)d_in[0];
    const float* emb    = (const float*)d_in[1];
    const float* W1     = (const float*)d_in[2];
    const float* U1     = (const float*)d_in[3];
    const float* b1     = (const float*)d_in[4];
    const float* W2     = (const float*)d_in[5];
    const float* U2     = (const float*)d_in[6];
    const float* b2     = (const float*)d_in[7];
    const float* Wd     = (const float*)d_in[8];
    const float* bd     = (const float*)d_in[9];
    float* out = (float*)d_out;

    char* ws = (char*)d_ws;
    float*          xwT = (float*)ws;                                  // 32 MB [b][col][t]
    unsigned short* h1  = (unsigned short*)(ws + (33554432));          // 16 MB bf16 [b][t][col]
    char*           p   = ws + 33554432 + 16777216;
    unsigned short* W1t = (unsigned short*)p;            p += 512 * 256 * 2;
    unsigned short* W2t = (unsigned short*)p;            p += 256 * 256 * 2;
    unsigned short* U1t = (unsigned short*)p;            p += 256 * 256 * 2;
    unsigned short* U2t = (unsigned short*)p;            p += 256 * 256 * 2;
    float*          h2  = (float*)p;

    const int M = 64 * 512;   // 32768

    // K0: weight/recurrence transposes to bf16 [N][K]
    transpose4<<<dim3(512, 4), 256, 0, stream>>>(W1, W2, U1, U2, W1t, W2t, U1t, U2t);

    // K1: xw1 = emb[tokens] @ W1 + b1   (gather fused, transposed store)
    gemm_mfma<true><<<dim3(256 / 64, M / 64), 256, 0, stream>>>(
        emb, tokens, W1t, b1, xwT, M, 256, 512);

    // K2: layer-1 scan -> h1 (bf16 sequence, [b][t][col]), 2 rows per WG
    rnn_scan_mfma2<true><<<32, 256, 0, stream>>>(xwT, U1t, h1, nullptr);

    // K3: xw2 = h1 @ W2 + b2   (transposed store)
    gemm_mfma<false><<<dim3(256 / 64, M / 64), 256, 0, stream>>>(
        h1, nullptr, W2t, b2, xwT, M, 256, 256);

    // K4: layer-2 scan -> h2 (last state, f32), 2 rows per WG
    rnn_scan_mfma2<false><<<32, 256, 0, stream>>>(xwT, U2t, nullptr, h2);

    // K5: softmax(h2 @ Wd + bd)
    head_kernel<<<1, 128, 0, stream>>>(h2, Wd, bd, out);
}

// Round 9
// 660.771 us; speedup vs baseline: 1.7329x; 1.7329x over previous
//
#include <hip/hip_runtime.h>

// ---------- types ----------
typedef __attribute__((ext_vector_type(8))) short bf16x8;
typedef __attribute__((ext_vector_type(4))) float f32x4;

static __device__ __forceinline__ unsigned short f2bf(float x) {
    unsigned int u = __float_as_uint(x);
    u += 0x7fffu + ((u >> 16) & 1u);   // RTNE, finite inputs
    return (unsigned short)(u >> 16);
}

// Workgroup barrier WITHOUT vmcnt drain: LDS ordering only.
// Safe when no global-memory producer/consumer relationship crosses the barrier.
static __device__ __forceinline__ void barrier_lds_only() {
    __asm__ volatile("s_waitcnt lgkmcnt(0)\n\ts_barrier" ::: "memory");
}

// ---------- K0: four fp32->bf16 transposes in one launch ----------
__global__ void transpose4(const float* __restrict__ s0, const float* __restrict__ s1,
                           const float* __restrict__ s2, const float* __restrict__ s3,
                           unsigned short* __restrict__ d0, unsigned short* __restrict__ d1,
                           unsigned short* __restrict__ d2, unsigned short* __restrict__ d3) {
    int which = blockIdx.y;
    const float* src = which == 0 ? s0 : which == 1 ? s1 : which == 2 ? s2 : s3;
    unsigned short* dst = which == 0 ? d0 : which == 1 ? d1 : which == 2 ? d2 : d3;
    int K = (which == 0) ? 512 : 256;
    int idx = blockIdx.x * 256 + threadIdx.x;
    if (idx >= K * 256) return;
    int k = idx >> 8;          // N = 256
    int n = idx & 255;
    dst[n * K + k] = f2bf(src[idx]);
}

// ---------- GEMM (m97-style 128x128 tile): C = A[M,K] @ Bt[N,K]^T + bias ----------
// 4 waves, each a 64x64 sub-tile (4x4 16x16x32 MFMAs per k-iter = 16 MFMA/wave/iter).
// Output stored TRANSPOSED as CT[b][n][t] (b = m>>9, t = m&511), t-contiguous float4.
template<bool GATHER>
__global__ __launch_bounds__(256, 2) void gemm_mfma_big(
    const void* __restrict__ Aptr, const int* __restrict__ tokens,
    const unsigned short* __restrict__ Bt, const float* __restrict__ bias,
    float* __restrict__ C, int M, int N, int K)
{
    const int bn0 = blockIdx.x * 128;
    const int m0  = blockIdx.y * 128;
    const int tid = threadIdx.x;

    __shared__ unsigned short As[128 * 40];   // 128 m-rows x 32 k, pad->40
    __shared__ unsigned short Bs[128 * 40];   // 128 n-rows x 32 k
    __shared__ int tok[128];

    if (GATHER) {
        if (tid < 128) tok[tid] = tokens[m0 + tid];
        __syncthreads();
    }

    const int r  = tid >> 1;          // staging row 0..127
    const int c0 = (tid & 1) * 16;    // k-offset 0 or 16
    const int w  = tid >> 6;          // wave 0..3
    const int L  = tid & 63;
    const int ml = L & 15;
    const int q  = L >> 4;
    const int wm = (w & 1) * 64;      // wave m-offset
    const int wn = (w >> 1) * 64;     // wave n-offset

    f32x4 acc[4][4] = {};             // [mt][nt]

    for (int k0 = 0; k0 < K; k0 += 32) {
        // ---- stage A tile (16 elems per thread) ----
        if (GATHER) {
            const float* src = (const float*)Aptr + (size_t)tok[r] * K + k0 + c0;
            float4 f0 = *(const float4*)(src);
            float4 f1 = *(const float4*)(src + 4);
            float4 f2 = *(const float4*)(src + 8);
            float4 f3 = *(const float4*)(src + 12);
            unsigned short t0[8], t1[8];
            t0[0]=f2bf(f0.x); t0[1]=f2bf(f0.y); t0[2]=f2bf(f0.z); t0[3]=f2bf(f0.w);
            t0[4]=f2bf(f1.x); t0[5]=f2bf(f1.y); t0[6]=f2bf(f1.z); t0[7]=f2bf(f1.w);
            t1[0]=f2bf(f2.x); t1[1]=f2bf(f2.y); t1[2]=f2bf(f2.z); t1[3]=f2bf(f2.w);
            t1[4]=f2bf(f3.x); t1[5]=f2bf(f3.y); t1[6]=f2bf(f3.z); t1[7]=f2bf(f3.w);
            *(uint4*)&As[r * 40 + c0]     = *(const uint4*)t0;
            *(uint4*)&As[r * 40 + c0 + 8] = *(const uint4*)t1;
        } else {
            const unsigned short* src = (const unsigned short*)Aptr + (size_t)(m0 + r) * K + k0 + c0;
            *(uint4*)&As[r * 40 + c0]     = ((const uint4*)src)[0];
            *(uint4*)&As[r * 40 + c0 + 8] = ((const uint4*)src)[1];
        }
        // ---- stage B tile ----
        const unsigned short* bs = Bt + (size_t)(bn0 + r) * K + k0 + c0;
        *(uint4*)&Bs[r * 40 + c0]     = ((const uint4*)bs)[0];
        *(uint4*)&Bs[r * 40 + c0 + 8] = ((const uint4*)bs)[1];
        __syncthreads();

        bf16x8 a[4], b[4];
#pragma unroll
        for (int mt = 0; mt < 4; ++mt)
            a[mt] = *(const bf16x8*)&As[(wm + mt * 16 + ml) * 40 + q * 8];
#pragma unroll
        for (int nt = 0; nt < 4; ++nt)
            b[nt] = *(const bf16x8*)&Bs[(wn + nt * 16 + ml) * 40 + q * 8];
#pragma unroll
        for (int mt = 0; mt < 4; ++mt)
#pragma unroll
            for (int nt = 0; nt < 4; ++nt)
                acc[mt][nt] = __builtin_amdgcn_mfma_f32_16x16x32_bf16(a[mt], b[nt], acc[mt][nt], 0, 0, 0);
        __syncthreads();
    }

    // Transposed epilogue: CT[b][gn][t]; lane holds 4 consecutive t per (mt,nt).
    const int bb = m0 >> 9;
    const int tb = (m0 & 511) + wm + q * 4;
#pragma unroll
    for (int nt = 0; nt < 4; ++nt) {
        int gn = bn0 + wn + nt * 16 + ml;
        float bv = bias[gn];
#pragma unroll
        for (int mt = 0; mt < 4; ++mt) {
            float4 v = { acc[mt][nt][0] + bv, acc[mt][nt][1] + bv,
                         acc[mt][nt][2] + bv, acc[mt][nt][3] + bv };
            *(float4*)&C[(size_t)bb * 131072 + (size_t)gn * 512 + tb + mt * 16] = v;
        }
    }
}

// ---------- MFMA scan: h_t = tanh(xwT_t + h_{t-1} @ U), one WG (256 thr) per batch row ----------
// (R7 structure, unchanged: 1 row/WG, double-buffered h, one lds-only barrier/step,
// chunked xw stream [b][col][t] with float4 = 4 timesteps loaded 2 groups ahead.)
template<bool SEQ>
__global__ __launch_bounds__(256, 1) void rnn_scan_mfma(
    const float* __restrict__ xwT,          // [64][256][512] f32 (transposed)
    const unsigned short* __restrict__ Ut,  // [256][256] bf16, Ut[n][k] = U[k][n]
    unsigned short* __restrict__ out_seq,   // bf16 [64][512][256]  (SEQ)
    float* __restrict__ out_last)           // f32 [64][256]        (!SEQ)
{
    const int b   = blockIdx.x;
    const int tid = threadIdx.x;
    const int w   = tid >> 6;       // wave 0..3
    const int L   = tid & 63;
    const int col = w * 64 + L;     // this thread's output column (L = q*16+ml)
    const int q   = L >> 4;
    const int ml  = L & 15;

    __shared__ unsigned short hsh[2][256];

    // B-frags: U columns for this wave's 4 n-tiles, all 8 k-tiles
    bf16x8 ufrag[4][8];
#pragma unroll
    for (int i = 0; i < 4; ++i) {
        const unsigned short* up = Ut + (size_t)((w * 4 + i) * 16 + ml) * 256 + q * 8;
#pragma unroll
        for (int kt = 0; kt < 8; ++kt)
            ufrag[i][kt] = *(const bf16x8*)(up + kt * 32);
    }

    hsh[0][tid] = 0;   // bf16 +0.0

    const float* xb = xwT + (size_t)b * 131072 + (size_t)col * 512;
    unsigned short* op = SEQ ? out_seq + (size_t)b * 512 * 256 + col : nullptr;

    // preload chunks 0 and 1 (t=0..7)
    float4 cch0 = *(const float4*)(xb);
    float4 cch1 = *(const float4*)(xb + 4);

    const f32x4 zf = {0.f, 0.f, 0.f, 0.f};  // loop-invariant zero C operand
    float lastv = 0.f;
    __syncthreads();

#define SCAN_STEP(CUR, XV)                                                           \
    {                                                                                \
        bf16x8 af[8];                                                                \
        _Pragma("unroll")                                                            \
        for (int kt = 0; kt < 8; ++kt)                                               \
            af[kt] = *(const bf16x8*)&hsh[CUR][kt * 32 + q * 8];                     \
        f32x4 accA[4], accB[4];                                                      \
        _Pragma("unroll")                                                            \
        for (int i = 0; i < 4; ++i)                                                  \
            accA[i] = __builtin_amdgcn_mfma_f32_16x16x32_bf16(af[0], ufrag[i][0], zf, 0, 0, 0); \
        _Pragma("unroll")                                                            \
        for (int i = 0; i < 4; ++i)                                                  \
            accB[i] = __builtin_amdgcn_mfma_f32_16x16x32_bf16(af[1], ufrag[i][1], zf, 0, 0, 0); \
        _Pragma("unroll")                                                            \
        for (int kt = 2; kt < 8; kt += 2) {                                          \
            _Pragma("unroll")                                                        \
            for (int i = 0; i < 4; ++i)                                              \
                accA[i] = __builtin_amdgcn_mfma_f32_16x16x32_bf16(af[kt], ufrag[i][kt], accA[i], 0, 0, 0);       \
            _Pragma("unroll")                                                        \
            for (int i = 0; i < 4; ++i)                                              \
                accB[i] = __builtin_amdgcn_mfma_f32_16x16x32_bf16(af[kt + 1], ufrag[i][kt + 1], accB[i], 0, 0, 0); \
        }                                                                            \
        float zA = (q == 0) ? accA[0][0] : (q == 1) ? accA[1][0] : (q == 2) ? accA[2][0] : accA[3][0]; \
        float zB = (q == 0) ? accB[0][0] : (q == 1) ? accB[1][0] : (q == 2) ? accB[2][0] : accB[3][0]; \
        float z  = zA + zB + (XV);                                                   \
        float e  = __expf(2.f * z);               /* tanh(z) = 1 - 2/(e^{2z}+1) */   \
        float hn = 1.f - 2.f * __builtin_amdgcn_rcpf(e + 1.f);                       \
        lastv = hn;                                                                  \
        unsigned short hb = f2bf(hn);                                                \
        hsh[(CUR) ^ 1][col] = hb;                                                    \
        if (SEQ) { *op = hb; op += 256; }                                            \
        barrier_lds_only();                       /* h_new visible; no vmcnt drain */\
    }

    // steady state: groups 0..125 consumed; loads issued 2 groups ahead
    for (int g = 0; g < 126; g += 2) {
        {
            float4 nx = *(const float4*)(xb + 4 * g + 8);
            SCAN_STEP(0, cch0.x)
            SCAN_STEP(1, cch0.y)
            SCAN_STEP(0, cch0.z)
            SCAN_STEP(1, cch0.w)
            cch0 = nx;
        }
        {
            float4 nx = *(const float4*)(xb + 4 * g + 12);
            SCAN_STEP(0, cch1.x)
            SCAN_STEP(1, cch1.y)
            SCAN_STEP(0, cch1.z)
            SCAN_STEP(1, cch1.w)
            cch1 = nx;
        }
    }
    // epilogue: groups 126, 127 (t = 504..511), no loads
    SCAN_STEP(0, cch0.x)
    SCAN_STEP(1, cch0.y)
    SCAN_STEP(0, cch0.z)
    SCAN_STEP(1, cch0.w)
    SCAN_STEP(0, cch1.x)
    SCAN_STEP(1, cch1.y)
    SCAN_STEP(0, cch1.z)
    SCAN_STEP(1, cch1.w)
#undef SCAN_STEP

    if (!SEQ) out_last[b * 256 + col] = lastv;
}

// ---------- head: softmax(h2 @ Wd + bd) ----------
__global__ void head_kernel(const float* __restrict__ h2, const float* __restrict__ Wd,
                            const float* __restrict__ bd, float* __restrict__ out)
{
    int tid = threadIdx.x;         // 128 threads: b = tid>>1, c = tid&1
    int b = tid >> 1, c = tid & 1;
    float s = bd[c];
    for (int jj = 0; jj < 256; ++jj) s = fmaf(h2[b * 256 + jj], Wd[jj * 2 + c], s);
    __shared__ float lg[128];
    lg[tid] = s;
    __syncthreads();
    float o0 = lg[b * 2 + 0], o1 = lg[b * 2 + 1];
    float m = fmaxf(o0, o1);
    float z = __expf(o0 - m) + __expf(o1 - m);
    out[tid] = __expf(s - m) * __builtin_amdgcn_rcpf(z);
}

// ---------- launch ----------
extern "C" void kernel_launch(void* const* d_in, const int* in_sizes, int n_in,
                              void* d_out, int out_size, void* d_ws, size_t ws_size,
                              hipStream_t stream) {
    const int*   tokens = (const int*)d_in[0];
    const float* emb    = (const float*)d_in[1];
    const float* W1     = (const float*)d_in[2];
    const float* U1     = (const float*)d_in[3];
    const float* b1     = (const float*)d_in[4];
    const float* W2     = (const float*)d_in[5];
    const float* U2     = (const float*)d_in[6];
    const float* b2     = (const float*)d_in[7];
    const float* Wd     = (const float*)d_in[8];
    const float* bd     = (const float*)d_in[9];
    float* out = (float*)d_out;

    char* ws = (char*)d_ws;
    float*          xwT = (float*)ws;                                  // 32 MB [b][col][t]
    unsigned short* h1  = (unsigned short*)(ws + (33554432));          // 16 MB bf16 [b][t][col]
    char*           p   = ws + 33554432 + 16777216;
    unsigned short* W1t = (unsigned short*)p;            p += 512 * 256 * 2;
    unsigned short* W2t = (unsigned short*)p;            p += 256 * 256 * 2;
    unsigned short* U1t = (unsigned short*)p;            p += 256 * 256 * 2;
    unsigned short* U2t = (unsigned short*)p;            p += 256 * 256 * 2;
    float*          h2  = (float*)p;

    const int M = 64 * 512;   // 32768

    // K0: weight/recurrence transposes to bf16 [N][K]
    transpose4<<<dim3(512, 4), 256, 0, stream>>>(W1, W2, U1, U2, W1t, W2t, U1t, U2t);

    // K1: xw1 = emb[tokens] @ W1 + b1   (gather fused, 128x128 tile, transposed store)
    gemm_mfma_big<true><<<dim3(256 / 128, M / 128), 256, 0, stream>>>(
        emb, tokens, W1t, b1, xwT, M, 256, 512);

    // K2: layer-1 scan -> h1 (bf16 sequence, [b][t][col])
    rnn_scan_mfma<true><<<64, 256, 0, stream>>>(xwT, U1t, h1, nullptr);

    // K3: xw2 = h1 @ W2 + b2   (128x128 tile, transposed store)
    gemm_mfma_big<false><<<dim3(256 / 128, M / 128), 256, 0, stream>>>(
        h1, nullptr, W2t, b2, xwT, M, 256, 256);

    // K4: layer-2 scan -> h2 (last state, f32)
    rnn_scan_mfma<false><<<64, 256, 0, stream>>>(xwT, U2t, nullptr, h2);

    // K5: softmax(h2 @ Wd + bd)
    head_kernel<<<1, 128, 0, stream>>>(h2, Wd, bd, out);
}